// Round 16
// baseline (249.491 us; speedup 1.0000x reference)
//
#include <hip/hip_runtime.h>
#include <hip/hip_bf16.h>

typedef short s8v __attribute__((ext_vector_type(8)));
typedef float f4v __attribute__((ext_vector_type(4)));

#define LDA 136  // padded LDS row (shorts)

// ---------- bf16 helpers ----------
__device__ __forceinline__ unsigned short f2bf(float f) {  // RNE
  unsigned int u = __builtin_bit_cast(unsigned int, f);
  unsigned int r = u + 0x7fffu + ((u >> 16) & 1u);
  return (unsigned short)(r >> 16);
}
__device__ __forceinline__ float bf2f(unsigned short s) {
  return __builtin_bit_cast(float, ((unsigned int)s) << 16);
}
__device__ __forceinline__ float bflo(unsigned int v) {
  return __builtin_bit_cast(float, (unsigned int)(v << 16));
}
__device__ __forceinline__ float bfhi(unsigned int v) {
  return __builtin_bit_cast(float, (unsigned int)(v & 0xffff0000u));
}
__device__ __forceinline__ unsigned int packbf(float a, float b) {
  return (unsigned int)f2bf(a) | ((unsigned int)f2bf(b) << 16);
}

__device__ __forceinline__ int lower_bound_i(const int* a, int n, int key) {
  int lo = 0, hi = n;
  while (lo < hi) { int mid = (lo + hi) >> 1; if (a[mid] < key) lo = mid + 1; else hi = mid; }
  return lo;
}

// ---------- gather: acc = h[i]*di + sum_s h[s]*dinv[s] ----------
__device__ __forceinline__ float gather_node(
    int i, int sub, const int* __restrict__ offs, const int* __restrict__ col,
    const float* __restrict__ dinv, const uint4* __restrict__ hu, float acc[8]) {
  float di = dinv[i];
  uint4 hv = hu[(size_t)i * 16 + sub];
  acc[0] = bflo(hv.x) * di; acc[1] = bfhi(hv.x) * di;
  acc[2] = bflo(hv.y) * di; acc[3] = bfhi(hv.y) * di;
  acc[4] = bflo(hv.z) * di; acc[5] = bfhi(hv.z) * di;
  acc[6] = bflo(hv.w) * di; acc[7] = bfhi(hv.w) * di;
  int b0 = offs[i], b1 = offs[i + 1];
  int e = b0;
  for (; e + 4 <= b1; e += 4) {
    int s0 = col[e], s1 = col[e + 1], s2 = col[e + 2], s3 = col[e + 3];
    uint4 h0 = hu[(size_t)s0 * 16 + sub];
    uint4 h1 = hu[(size_t)s1 * 16 + sub];
    uint4 h2 = hu[(size_t)s2 * 16 + sub];
    uint4 h3 = hu[(size_t)s3 * 16 + sub];
    float n0 = dinv[s0], n1 = dinv[s1], n2 = dinv[s2], n3 = dinv[s3];
    acc[0] += bflo(h0.x) * n0 + bflo(h1.x) * n1 + bflo(h2.x) * n2 + bflo(h3.x) * n3;
    acc[1] += bfhi(h0.x) * n0 + bfhi(h1.x) * n1 + bfhi(h2.x) * n2 + bfhi(h3.x) * n3;
    acc[2] += bflo(h0.y) * n0 + bflo(h1.y) * n1 + bflo(h2.y) * n2 + bflo(h3.y) * n3;
    acc[3] += bfhi(h0.y) * n0 + bfhi(h1.y) * n1 + bfhi(h2.y) * n2 + bfhi(h3.y) * n3;
    acc[4] += bflo(h0.z) * n0 + bflo(h1.z) * n1 + bflo(h2.z) * n2 + bflo(h3.z) * n3;
    acc[5] += bfhi(h0.z) * n0 + bfhi(h1.z) * n1 + bfhi(h2.z) * n2 + bfhi(h3.z) * n3;
    acc[6] += bflo(h0.w) * n0 + bflo(h1.w) * n1 + bflo(h2.w) * n2 + bflo(h3.w) * n3;
    acc[7] += bfhi(h0.w) * n0 + bfhi(h1.w) * n1 + bfhi(h2.w) * n2 + bfhi(h3.w) * n3;
  }
  for (; e < b1; ++e) {
    int s0 = col[e];
    uint4 h0 = hu[(size_t)s0 * 16 + sub];
    float n0 = dinv[s0];
    acc[0] += bflo(h0.x) * n0; acc[1] += bfhi(h0.x) * n0;
    acc[2] += bflo(h0.y) * n0; acc[3] += bfhi(h0.y) * n0;
    acc[4] += bflo(h0.z) * n0; acc[5] += bfhi(h0.z) * n0;
    acc[6] += bflo(h0.w) * n0; acc[7] += bfhi(h0.w) * n0;
  }
  return di;
}

__device__ __forceinline__ uint4 ln_relu_pack(
    float v[8], int sub, const float* __restrict__ gam, const float* __restrict__ bet) {
  float s = 0.f, q = 0.f;
#pragma unroll
  for (int j = 0; j < 8; ++j) { s += v[j]; q += v[j] * v[j]; }
#pragma unroll
  for (int o = 1; o < 16; o <<= 1) {
    s += __shfl_xor(s, o);
    q += __shfl_xor(q, o);
  }
  float m = s * (1.0f / 128.0f);
  float var = q * (1.0f / 128.0f) - m * m;
  float rs = rsqrtf(var + 1e-5f);
  float4 g0 = reinterpret_cast<const float4*>(gam)[sub * 2];
  float4 g1 = reinterpret_cast<const float4*>(gam)[sub * 2 + 1];
  float4 e0 = reinterpret_cast<const float4*>(bet)[sub * 2];
  float4 e1 = reinterpret_cast<const float4*>(bet)[sub * 2 + 1];
  uint4 ov;
  ov.x = packbf(fmaxf((v[0] - m) * rs * g0.x + e0.x, 0.f), fmaxf((v[1] - m) * rs * g0.y + e0.y, 0.f));
  ov.y = packbf(fmaxf((v[2] - m) * rs * g0.z + e0.z, 0.f), fmaxf((v[3] - m) * rs * g0.w + e0.w, 0.f));
  ov.z = packbf(fmaxf((v[4] - m) * rs * g1.x + e1.x, 0.f), fmaxf((v[5] - m) * rs * g1.y + e1.y, 0.f));
  ov.w = packbf(fmaxf((v[6] - m) * rs * g1.z + e1.z, 0.f), fmaxf((v[7] - m) * rs * g1.w + e1.w, 0.f));
  return ov;
}

__device__ __forceinline__ void scale_bias(
    float acc[8], float di, int sub, const float* __restrict__ bias, float v[8]) {
  float4 b0v = reinterpret_cast<const float4*>(bias)[sub * 2];
  float4 b1v = reinterpret_cast<const float4*>(bias)[sub * 2 + 1];
  v[0] = acc[0] * di + b0v.x; v[1] = acc[1] * di + b0v.y;
  v[2] = acc[2] * di + b0v.z; v[3] = acc[3] * di + b0v.w;
  v[4] = acc[4] * di + b1v.x; v[5] = acc[5] * di + b1v.y;
  v[6] = acc[6] * di + b1v.z; v[7] = acc[7] * di + b1v.w;
}

// degree-sort 32 nodes of this block into perm (rank -> local idx)
__device__ __forceinline__ void build_perm(
    int blk, int n, const int* __restrict__ offs, int tid, int* degs, int* perm) {
  if (tid < 32) {
    int i = blk + tid;
    degs[tid] = (i < n) ? (offs[i + 1] - offs[i]) : -1;
  }
  __syncthreads();
  if (tid < 32) {
    int d = degs[tid];
    int rank = 0;
#pragma unroll
    for (int j = 0; j < 32; ++j) {
      int dj = degs[j];
      rank += (dj < d) || (dj == d && j < tid);
    }
    perm[rank] = tid;
  }
  __syncthreads();
}

// ---------- K1: weight pack (384 blocks) + bucket histogram (64 blocks) ----------
__global__ __launch_bounds__(256) void packhist(
    const float* __restrict__ Wa, const float* __restrict__ Wb, const float* __restrict__ Wc,
    unsigned short* __restrict__ P, const int* __restrict__ dst,
    unsigned int* __restrict__ Hist, int E) {
  __shared__ unsigned int cnt[256];
  int bid = blockIdx.x;
  int t = threadIdx.x;
  if (bid >= 384) {
    int hb = bid - 384;
    cnt[t] = 0u;
    __syncthreads();
    int chunk = (E + 63) >> 6;
    int lo = hb * chunk, hi = min(E, lo + chunk);
    for (int e = lo + t; e < hi; e += 256)
      atomicAdd(&cnt[((unsigned int)dst[e]) >> 8], 1u);
    __syncthreads();
    Hist[hb * 256 + t] = cnt[t];
    return;
  }
  int gidx = bid * 256 + t;
  int which = gidx >> 15;
  int idx = gidx & 32767;
  const float* W = (which == 0) ? Wa : (which == 1) ? Wb : Wc;
  int j = idx & 15;
  int lane = (idx >> 4) & 63;
  int tt = (idx >> 10) & 7;
  int c = (idx >> 13) & 3;
  int k = c * 32 + (lane >> 4) * 8 + (j & 7);
  int nn = tt * 16 + (lane & 15);
  float f = W[k * 128 + nn];
  unsigned short hi16 = f2bf(f);
  unsigned short outv = (j < 8) ? hi16 : f2bf(f - bf2f(hi16));
  P[gidx] = outv;
}

// ---------- K2: per-(block,bucket) bases + bucket starts (1 block) ----------
__global__ __launch_bounds__(256) void scanbase(
    unsigned int* __restrict__ Hist, unsigned int* __restrict__ Base,
    unsigned int* __restrict__ Bstart, int* __restrict__ offs, int n, int E) {
  __shared__ int sh[256];
  int t = threadIdx.x;
  unsigned int run = 0;
  for (int b = 0; b < 64; ++b) {
    Base[b * 256 + t] = run;
    run += Hist[b * 256 + t];
  }
  int v = (int)run;
  sh[t] = v;
  __syncthreads();
  for (int o = 1; o < 256; o <<= 1) {
    int add = (t >= o) ? sh[t - o] : 0;
    __syncthreads();
    sh[t] += add;
    __syncthreads();
  }
  unsigned int pre = (unsigned int)(sh[t] - v);
  Bstart[t] = pre;
  for (int b = 0; b < 64; ++b) Base[b * 256 + t] += pre;
  if (t == 0) offs[n] = E;
}

// ---------- K3: layer-1 GEMM + bucket scatter ----------
__global__ __launch_bounds__(256) void gemm1_scatter(
    const float* __restrict__ in, const unsigned short* __restrict__ P,
    unsigned short* __restrict__ out, int n,
    const int* __restrict__ src, const int* __restrict__ dst,
    const unsigned int* __restrict__ Base, unsigned int* __restrict__ EP,
    int E, int gemmBlocks) {
  __shared__ unsigned int cur[256];
  int tid = threadIdx.x;
  if ((int)blockIdx.x >= gemmBlocks) {
    int sb = (int)blockIdx.x - gemmBlocks;
    cur[tid] = Base[sb * 256 + tid];
    __syncthreads();
    int chunk = (E + 63) >> 6;
    int lo = sb * chunk, hi = min(E, lo + chunk);
    for (int e = lo + tid; e < hi; e += 256) {
      unsigned int d = (unsigned int)dst[e];
      unsigned int s = (unsigned int)src[e];
      unsigned int pos = atomicAdd(&cur[d >> 8], 1u);
      EP[pos] = ((d & 255u) << 16) | s;  // N <= 65536
    }
    return;
  }
  int wave = tid >> 6, lane = tid & 63;
  int quad = lane >> 4, c16 = lane & 15;
  int base = blockIdx.x * 64 + wave * 16;
  int m = base + c16;

  f4v acc[8];
#pragma unroll
  for (int t = 0; t < 8; ++t) acc[t] = (f4v){0.f, 0.f, 0.f, 0.f};

  for (int c = 0; c < 4; ++c) {
    s8v ah, al;
    float v[8];
    if (m < n) {
      const float4* xp = reinterpret_cast<const float4*>(in + (size_t)m * 128 + c * 32 + quad * 8);
      float4 v0 = xp[0], v1 = xp[1];
      v[0] = v0.x; v[1] = v0.y; v[2] = v0.z; v[3] = v0.w;
      v[4] = v1.x; v[5] = v1.y; v[6] = v1.z; v[7] = v1.w;
    } else {
#pragma unroll
      for (int j = 0; j < 8; ++j) v[j] = 0.f;
    }
#pragma unroll
    for (int j = 0; j < 8; ++j) {
      unsigned short h = f2bf(v[j]);
      ah[j] = (short)h;
      al[j] = (short)f2bf(v[j] - bf2f(h));
    }
#pragma unroll
    for (int t = 0; t < 8; ++t) {
      const s8v* bp = reinterpret_cast<const s8v*>(&P[((c * 8 + t) * 64 + lane) * 16]);
      s8v bh = bp[0], bl = bp[1];
      acc[t] = __builtin_amdgcn_mfma_f32_16x16x32_bf16(ah, bh, acc[t], 0, 0, 0);
      acc[t] = __builtin_amdgcn_mfma_f32_16x16x32_bf16(ah, bl, acc[t], 0, 0, 0);
      acc[t] = __builtin_amdgcn_mfma_f32_16x16x32_bf16(al, bh, acc[t], 0, 0, 0);
    }
  }
#pragma unroll
  for (int t = 0; t < 8; ++t)
#pragma unroll
    for (int r = 0; r < 4; ++r) {
      int mm = base + quad * 4 + r;
      if (mm < n) out[(size_t)mm * 128 + t * 16 + c16] = f2bf(acc[t][r]);
    }
}

// ---------- K4: per-bucket fine CSR ----------
__global__ __launch_bounds__(256) void fine_csr(
    const unsigned int* __restrict__ EP, const unsigned int* __restrict__ Bstart,
    int* __restrict__ offs, float* __restrict__ dinv, int* __restrict__ col, int n) {
  __shared__ unsigned int cnt[256];
  __shared__ int sh[256];
  __shared__ unsigned int cur[256];
  int bk = blockIdx.x;
  int t = threadIdx.x;
  unsigned int rlo = Bstart[bk];
  unsigned int rhi = (bk < 255) ? Bstart[bk + 1] : rlo;
  cnt[t] = 0u;
  __syncthreads();
  for (unsigned int i = rlo + t; i < rhi; i += 256)
    atomicAdd(&cnt[EP[i] >> 16], 1u);
  __syncthreads();
  int v = (int)cnt[t];
  sh[t] = v;
  __syncthreads();
  for (int o = 1; o < 256; o <<= 1) {
    int add = (t >= o) ? sh[t - o] : 0;
    __syncthreads();
    sh[t] += add;
    __syncthreads();
  }
  int pre = sh[t] - v;
  int node = bk * 256 + t;
  if (node < n) {
    offs[node] = (int)(rlo + pre);
    dinv[node] = rsqrtf((float)(v + 1));
  }
  cur[t] = rlo + (unsigned int)pre;
  __syncthreads();
  for (unsigned int i = rlo + t; i < rhi; i += 256) {
    unsigned int w = EP[i];
    unsigned int dl = w >> 16;
    unsigned int pos = atomicAdd(&cur[dl], 1u);
    col[pos] = (int)(w & 0xffffu);
  }
}

// ---------- K5: fused gather1+LN (degree-sorted) -> LDS -> GEMM(W2) -> out ----------
__global__ __launch_bounds__(256) void gather_gemm(
    const int* __restrict__ offs, const int* __restrict__ col,
    const float* __restrict__ dinv, const unsigned short* __restrict__ h,
    const float* __restrict__ bias, const float* __restrict__ gam,
    const float* __restrict__ bet, const unsigned short* __restrict__ P,
    unsigned short* __restrict__ out, int n) {
  __shared__ unsigned short A[32 * LDA];
  __shared__ int degs[32];
  __shared__ int perm[32];
  int tid = threadIdx.x;
  int wave = tid >> 6, lane = tid & 63;
  int grp = lane >> 4, sub = lane & 15;
  const uint4* hu = reinterpret_cast<const uint4*>(h);
  int blk = blockIdx.x * 32;
  build_perm(blk, n, offs, tid, degs, perm);
  for (int it = 0; it < 2; ++it) {
    int li = perm[it * 16 + wave * 4 + grp];
    int i = blk + li;
    uint4 ov;
    if (i < n) {
      float acc[8], v[8];
      float di = gather_node(i, sub, offs, col, dinv, hu, acc);
      scale_bias(acc, di, sub, bias, v);
      ov = ln_relu_pack(v, sub, gam, bet);
    } else {
      ov = make_uint4(0u, 0u, 0u, 0u);
    }
    *reinterpret_cast<uint4*>(&A[li * LDA + sub * 8]) = ov;
  }
  __syncthreads();
  int quad = lane >> 4, c16 = lane & 15;
  int rowgrp = wave & 1, colhalf = wave >> 1;
  f4v acc[4];
#pragma unroll
  for (int t = 0; t < 4; ++t) acc[t] = (f4v){0.f, 0.f, 0.f, 0.f};
  int liA = rowgrp * 16 + c16;
  for (int c = 0; c < 4; ++c) {
    s8v ah = *reinterpret_cast<const s8v*>(&A[liA * LDA + c * 32 + quad * 8]);
#pragma unroll
    for (int t4 = 0; t4 < 4; ++t4) {
      int t = colhalf * 4 + t4;
      const s8v* bp = reinterpret_cast<const s8v*>(&P[((c * 8 + t) * 64 + lane) * 16]);
      s8v bh = bp[0], bl = bp[1];
      acc[t4] = __builtin_amdgcn_mfma_f32_16x16x32_bf16(ah, bh, acc[t4], 0, 0, 0);
      acc[t4] = __builtin_amdgcn_mfma_f32_16x16x32_bf16(ah, bl, acc[t4], 0, 0, 0);
    }
  }
#pragma unroll
  for (int t4 = 0; t4 < 4; ++t4) {
    int t = colhalf * 4 + t4;
#pragma unroll
    for (int r = 0; r < 4; ++r) {
      int mm = blk + rowgrp * 16 + quad * 4 + r;
      if (mm < n) out[(size_t)mm * 128 + t * 16 + c16] = f2bf(acc[t4][r]);
    }
  }
}

// ---------- K6: fused gather2+LN (degree-sorted, +hout) + gate GEMM -> gate[N] ----------
__global__ __launch_bounds__(256) void gather_gate(
    const int* __restrict__ offs, const int* __restrict__ col,
    const float* __restrict__ dinv, const unsigned short* __restrict__ h,
    const float* __restrict__ bias, const float* __restrict__ gam,
    const float* __restrict__ bet, const unsigned short* __restrict__ P,
    const float* __restrict__ gb1, const float* __restrict__ gw2,
    const float* __restrict__ gb2, unsigned short* __restrict__ hout,
    float* __restrict__ gate, int n) {
  __shared__ unsigned short A[32 * LDA];
  __shared__ float pbuf[4][16];
  __shared__ int degs[32];
  __shared__ int perm[32];
  int tid = threadIdx.x;
  int wave = tid >> 6, lane = tid & 63;
  int grp = lane >> 4, sub = lane & 15;
  const uint4* hu = reinterpret_cast<const uint4*>(h);
  int blk = blockIdx.x * 32;
  build_perm(blk, n, offs, tid, degs, perm);
  for (int it = 0; it < 2; ++it) {
    int li = perm[it * 16 + wave * 4 + grp];
    int i = blk + li;
    uint4 ov;
    if (i < n) {
      float acc[8], v[8];
      float di = gather_node(i, sub, offs, col, dinv, hu, acc);
      scale_bias(acc, di, sub, bias, v);
      ov = ln_relu_pack(v, sub, gam, bet);
      reinterpret_cast<uint4*>(hout)[(size_t)i * 16 + sub] = ov;
    } else {
      ov = make_uint4(0u, 0u, 0u, 0u);
    }
    *reinterpret_cast<uint4*>(&A[li * LDA + sub * 8]) = ov;
  }
  __syncthreads();
  int quad = lane >> 4, c16 = lane & 15;
  int rowgrp = wave & 1, colhalf = wave >> 1;
  f4v acc[4];
#pragma unroll
  for (int t = 0; t < 4; ++t) acc[t] = (f4v){0.f, 0.f, 0.f, 0.f};
  int liA = rowgrp * 16 + c16;
  for (int c = 0; c < 4; ++c) {
    s8v ah = *reinterpret_cast<const s8v*>(&A[liA * LDA + c * 32 + quad * 8]);
#pragma unroll
    for (int t4 = 0; t4 < 4; ++t4) {
      int t = colhalf * 4 + t4;
      const s8v* bp = reinterpret_cast<const s8v*>(&P[((c * 8 + t) * 64 + lane) * 16]);
      s8v bh = bp[0], bl = bp[1];
      acc[t4] = __builtin_amdgcn_mfma_f32_16x16x32_bf16(ah, bh, acc[t4], 0, 0, 0);
      acc[t4] = __builtin_amdgcn_mfma_f32_16x16x32_bf16(ah, bl, acc[t4], 0, 0, 0);
    }
  }
  float bv[4], g2[4];
#pragma unroll
  for (int t4 = 0; t4 < 4; ++t4) {
    int t = colhalf * 4 + t4;
    bv[t4] = gb1[t * 16 + c16];
    g2[t4] = gw2[t * 16 + c16];
  }
#pragma unroll
  for (int r = 0; r < 4; ++r) {
    float p = 0.f;
#pragma unroll
    for (int t4 = 0; t4 < 4; ++t4)
      p += fmaxf(acc[t4][r] + bv[t4], 0.f) * g2[t4];
#pragma unroll
    for (int o = 1; o < 16; o <<= 1) p += __shfl_xor(p, o);
    if (c16 == 0) pbuf[wave][quad * 4 + r] = p;
  }
  __syncthreads();
  if (tid < 32) {
    int rg = tid >> 4, local = tid & 15;
    int mm = blk + tid;
    if (mm < n) gate[mm] = pbuf[rg][local] + pbuf[rg + 2][local] + gb2[0];
  }
}

// ---------- pooling + classifier fused ----------
__global__ __launch_bounds__(256) void pool_cls(
    float* __restrict__ gate, const unsigned short* __restrict__ h,
    const int* __restrict__ batch,
    const float* __restrict__ w1, const float* __restrict__ b1,
    const float* __restrict__ w2, const float* __restrict__ b2,
    float* __restrict__ out, int n) {
  int g = blockIdx.x;
  int tid = threadIdx.x;
  __shared__ float red[256];
  __shared__ float red2[256];
  __shared__ float p[128];
  __shared__ float r[128];
  int lo = lower_bound_i(batch, n, g);
  int hi = lower_bound_i(batch, n, g + 1);
  if (lo >= hi) {
    if (tid < 128) p[tid] = 0.0f;
  } else {
    float m = -3.0e38f;
    for (int i = lo + tid; i < hi; i += 256) m = fmaxf(m, gate[i]);
    red[tid] = m;
    __syncthreads();
#pragma unroll
    for (int o = 128; o > 0; o >>= 1) {
      if (tid < o) red[tid] = fmaxf(red[tid], red[tid + o]);
      __syncthreads();
    }
    m = red[0];
    __syncthreads();
    float s = 0.0f;
    for (int i = lo + tid; i < hi; i += 256) {
      float e = __expf(gate[i] - m);
      gate[i] = e;
      s += e;
    }
    red[tid] = s;
    __syncthreads();
#pragma unroll
    for (int o = 128; o > 0; o >>= 1) {
      if (tid < o) red[tid] += red[tid + o];
      __syncthreads();
    }
    float inv = 1.0f / red[0];
    __syncthreads();
    const unsigned int* hu = reinterpret_cast<const unsigned int*>(h);
    int j = tid & 63, rgp = tid >> 6;
    float a0 = 0.f, a1 = 0.f;
    int i = lo + rgp;
    for (; i + 12 < hi; i += 16) {
      unsigned int p0 = hu[(size_t)i * 64 + j];
      unsigned int p1 = hu[(size_t)(i + 4) * 64 + j];
      unsigned int p2 = hu[(size_t)(i + 8) * 64 + j];
      unsigned int p3 = hu[(size_t)(i + 12) * 64 + j];
      float w0 = gate[i], w1v = gate[i + 4], w2v = gate[i + 8], w3v = gate[i + 12];
      a0 += bflo(p0) * w0 + bflo(p1) * w1v + bflo(p2) * w2v + bflo(p3) * w3v;
      a1 += bfhi(p0) * w0 + bfhi(p1) * w1v + bfhi(p2) * w2v + bfhi(p3) * w3v;
    }
    for (; i < hi; i += 4) {
      unsigned int p0 = hu[(size_t)i * 64 + j];
      float w0 = gate[i];
      a0 += bflo(p0) * w0;
      a1 += bfhi(p0) * w0;
    }
    red[tid] = a0;
    red2[tid] = a1;
    __syncthreads();
    if (tid < 64) {
      p[2 * tid]     = (red[tid] + red[tid + 64] + red[tid + 128] + red[tid + 192]) * inv;
      p[2 * tid + 1] = (red2[tid] + red2[tid + 64] + red2[tid + 128] + red2[tid + 192]) * inv;
    }
  }
  __syncthreads();
  int j = tid & 127, half = tid >> 7;
  float acc = 0.0f;
#pragma unroll 8
  for (int k = half * 64; k < half * 64 + 64; ++k)
    acc = fmaf(p[k], w1[k * 128 + j], acc);
  red[tid] = acc;
  __syncthreads();
  if (tid < 128) r[tid] = fmaxf(red[tid] + red[tid + 128] + b1[tid], 0.0f);
  __syncthreads();
  if (tid < 2) {
    float a = 0.0f;
    for (int k = 0; k < 128; ++k) a = fmaf(r[k], w2[k * 2 + tid], a);
    out[g * 2 + tid] = a + b2[tid];
  }
}

static inline size_t alup(size_t x) { return (x + 255) & ~(size_t)255; }

extern "C" void kernel_launch(void* const* d_in, const int* in_sizes, int n_in,
                              void* d_out, int out_size, void* d_ws, size_t ws_size,
                              hipStream_t stream) {
  const float* x    = (const float*)d_in[0];
  const int*   ei   = (const int*)d_in[1];
  const int*   bat  = (const int*)d_in[2];
  const float* W1   = (const float*)d_in[3];
  const float* b1   = (const float*)d_in[4];
  const float* ln1g = (const float*)d_in[5];
  const float* ln1b = (const float*)d_in[6];
  const float* W2   = (const float*)d_in[7];
  const float* b2   = (const float*)d_in[8];
  const float* ln2g = (const float*)d_in[9];
  const float* ln2b = (const float*)d_in[10];
  const float* gw1  = (const float*)d_in[11];
  const float* gb1  = (const float*)d_in[12];
  const float* gw2  = (const float*)d_in[13];
  const float* gb2  = (const float*)d_in[14];
  const float* cw1  = (const float*)d_in[15];
  const float* cb1  = (const float*)d_in[16];
  const float* cw2  = (const float*)d_in[17];
  const float* cb2  = (const float*)d_in[18];

  const int N = in_sizes[2];
  const int E = in_sizes[1] / 2;
  const int G = out_size / 2;
  const int* src = ei;
  const int* dst = ei + E;

  int mfmaB = (N + 63) / 64;
  int fuseB = (N + 31) / 32;
  int NB = (N + 255) / 256;

  char* base = (char*)d_ws;
  unsigned int* Hist = (unsigned int*)base;   base += alup((size_t)64 * 256 * 4);
  unsigned int* Base = (unsigned int*)base;   base += alup((size_t)64 * 256 * 4);
  unsigned int* Bstart = (unsigned int*)base; base += alup((size_t)256 * 4);
  unsigned int* EP = (unsigned int*)base;     base += alup((size_t)E * 4);
  float* dinv = (float*)base;                 base += alup((size_t)N * 4);
  int* offs = (int*)base;                     base += alup((size_t)(N + 1) * 4);
  int* col = (int*)base;                      base += alup((size_t)E * 4);
  unsigned short* pW = (unsigned short*)base; base += alup((size_t)3 * 32768 * 2);
  unsigned short* hbuf = (unsigned short*)base;  base += alup((size_t)N * 128 * 2);
  unsigned short* hbuf2 = (unsigned short*)base; base += alup((size_t)N * 128 * 2);
  unsigned short* hout = (unsigned short*)base;  base += alup((size_t)N * 128 * 2);
  float* gate = (float*)base;                 base += alup((size_t)N * 4);

  unsigned short* pW1 = pW;
  unsigned short* pW2 = pW + 32768;
  unsigned short* pG1 = pW + 65536;

  float* out = (float*)d_out;

  packhist<<<384 + 64, 256, 0, stream>>>(W1, W2, gw1, pW, dst, Hist, E);
  scanbase<<<1, 256, 0, stream>>>(Hist, Base, Bstart, offs, N, E);
  gemm1_scatter<<<mfmaB + 64, 256, 0, stream>>>(x, pW1, hbuf, N,
                                                src, dst, Base, EP, E, mfmaB);
  fine_csr<<<NB, 256, 0, stream>>>(EP, Bstart, offs, dinv, col, N);
  gather_gemm<<<fuseB, 256, 0, stream>>>(offs, col, dinv, hbuf, b1, ln1g, ln1b,
                                         pW2, hbuf2, N);
  gather_gate<<<fuseB, 256, 0, stream>>>(offs, col, dinv, hbuf2, b2, ln2g, ln2b,
                                         pG1, gb1, gw2, gb2, hout, gate, N);
  pool_cls<<<G, 256, 0, stream>>>(gate, hout, bat, cw1, cb1, cw2, cb2, out, N);
}

// Round 17
// 245.203 us; speedup vs baseline: 1.0175x; 1.0175x over previous
//
#include <hip/hip_runtime.h>
#include <hip/hip_bf16.h>

typedef short s8v __attribute__((ext_vector_type(8)));
typedef float f4v __attribute__((ext_vector_type(4)));

#define LDA 136  // padded LDS row (shorts)

// ---------- bf16 helpers ----------
__device__ __forceinline__ unsigned short f2bf(float f) {  // RNE
  unsigned int u = __builtin_bit_cast(unsigned int, f);
  unsigned int r = u + 0x7fffu + ((u >> 16) & 1u);
  return (unsigned short)(r >> 16);
}
__device__ __forceinline__ float bf2f(unsigned short s) {
  return __builtin_bit_cast(float, ((unsigned int)s) << 16);
}
__device__ __forceinline__ float bflo(unsigned int v) {
  return __builtin_bit_cast(float, (unsigned int)(v << 16));
}
__device__ __forceinline__ float bfhi(unsigned int v) {
  return __builtin_bit_cast(float, (unsigned int)(v & 0xffff0000u));
}
__device__ __forceinline__ unsigned int packbf(float a, float b) {
  return (unsigned int)f2bf(a) | ((unsigned int)f2bf(b) << 16);
}

__device__ __forceinline__ int lower_bound_i(const int* a, int n, int key) {
  int lo = 0, hi = n;
  while (lo < hi) { int mid = (lo + hi) >> 1; if (a[mid] < key) lo = mid + 1; else hi = mid; }
  return lo;
}

// ---------- gather with dinv[s] loads: acc = h[i]*di + sum_s h[s]*dinv[s] ----------
__device__ __forceinline__ float gather_node(
    int i, int sub, const int* __restrict__ offs, const int* __restrict__ col,
    const float* __restrict__ dinv, const uint4* __restrict__ hu, float acc[8]) {
  float di = dinv[i];
  uint4 hv = hu[(size_t)i * 16 + sub];
  acc[0] = bflo(hv.x) * di; acc[1] = bfhi(hv.x) * di;
  acc[2] = bflo(hv.y) * di; acc[3] = bfhi(hv.y) * di;
  acc[4] = bflo(hv.z) * di; acc[5] = bfhi(hv.z) * di;
  acc[6] = bflo(hv.w) * di; acc[7] = bfhi(hv.w) * di;
  int b0 = offs[i], b1 = offs[i + 1];
  int e = b0;
  for (; e + 4 <= b1; e += 4) {
    int s0 = col[e], s1 = col[e + 1], s2 = col[e + 2], s3 = col[e + 3];
    uint4 h0 = hu[(size_t)s0 * 16 + sub];
    uint4 h1 = hu[(size_t)s1 * 16 + sub];
    uint4 h2 = hu[(size_t)s2 * 16 + sub];
    uint4 h3 = hu[(size_t)s3 * 16 + sub];
    float n0 = dinv[s0], n1 = dinv[s1], n2 = dinv[s2], n3 = dinv[s3];
    acc[0] += bflo(h0.x) * n0 + bflo(h1.x) * n1 + bflo(h2.x) * n2 + bflo(h3.x) * n3;
    acc[1] += bfhi(h0.x) * n0 + bfhi(h1.x) * n1 + bfhi(h2.x) * n2 + bfhi(h3.x) * n3;
    acc[2] += bflo(h0.y) * n0 + bflo(h1.y) * n1 + bflo(h2.y) * n2 + bflo(h3.y) * n3;
    acc[3] += bfhi(h0.y) * n0 + bfhi(h1.y) * n1 + bfhi(h2.y) * n2 + bfhi(h3.y) * n3;
    acc[4] += bflo(h0.z) * n0 + bflo(h1.z) * n1 + bflo(h2.z) * n2 + bflo(h3.z) * n3;
    acc[5] += bfhi(h0.z) * n0 + bfhi(h1.z) * n1 + bfhi(h2.z) * n2 + bfhi(h3.z) * n3;
    acc[6] += bflo(h0.w) * n0 + bflo(h1.w) * n1 + bflo(h2.w) * n2 + bflo(h3.w) * n3;
    acc[7] += bfhi(h0.w) * n0 + bfhi(h1.w) * n1 + bfhi(h2.w) * n2 + bfhi(h3.w) * n3;
  }
  for (; e < b1; ++e) {
    int s0 = col[e];
    uint4 h0 = hu[(size_t)s0 * 16 + sub];
    float n0 = dinv[s0];
    acc[0] += bflo(h0.x) * n0; acc[1] += bfhi(h0.x) * n0;
    acc[2] += bflo(h0.y) * n0; acc[3] += bfhi(h0.y) * n0;
    acc[4] += bflo(h0.z) * n0; acc[5] += bfhi(h0.z) * n0;
    acc[6] += bflo(h0.w) * n0; acc[7] += bfhi(h0.w) * n0;
  }
  return di;
}

// ---------- pure-sum gather (rows pre-scaled by dinv[src]): acc = h'[i] + sum h'[s] ----------
__device__ __forceinline__ void gather_sum(
    int i, int sub, const int* __restrict__ offs, const int* __restrict__ col,
    const uint4* __restrict__ hu, float acc[8]) {
  uint4 hv = hu[(size_t)i * 16 + sub];
  acc[0] = bflo(hv.x); acc[1] = bfhi(hv.x);
  acc[2] = bflo(hv.y); acc[3] = bfhi(hv.y);
  acc[4] = bflo(hv.z); acc[5] = bfhi(hv.z);
  acc[6] = bflo(hv.w); acc[7] = bfhi(hv.w);
  int b0 = offs[i], b1 = offs[i + 1];
  int e = b0;
  for (; e + 4 <= b1; e += 4) {
    int s0 = col[e], s1 = col[e + 1], s2 = col[e + 2], s3 = col[e + 3];
    uint4 h0 = hu[(size_t)s0 * 16 + sub];
    uint4 h1 = hu[(size_t)s1 * 16 + sub];
    uint4 h2 = hu[(size_t)s2 * 16 + sub];
    uint4 h3 = hu[(size_t)s3 * 16 + sub];
    acc[0] += bflo(h0.x) + bflo(h1.x) + bflo(h2.x) + bflo(h3.x);
    acc[1] += bfhi(h0.x) + bfhi(h1.x) + bfhi(h2.x) + bfhi(h3.x);
    acc[2] += bflo(h0.y) + bflo(h1.y) + bflo(h2.y) + bflo(h3.y);
    acc[3] += bfhi(h0.y) + bfhi(h1.y) + bfhi(h2.y) + bfhi(h3.y);
    acc[4] += bflo(h0.z) + bflo(h1.z) + bflo(h2.z) + bflo(h3.z);
    acc[5] += bfhi(h0.z) + bfhi(h1.z) + bfhi(h2.z) + bfhi(h3.z);
    acc[6] += bflo(h0.w) + bflo(h1.w) + bflo(h2.w) + bflo(h3.w);
    acc[7] += bfhi(h0.w) + bfhi(h1.w) + bfhi(h2.w) + bfhi(h3.w);
  }
  for (; e < b1; ++e) {
    int s0 = col[e];
    uint4 h0 = hu[(size_t)s0 * 16 + sub];
    acc[0] += bflo(h0.x); acc[1] += bfhi(h0.x);
    acc[2] += bflo(h0.y); acc[3] += bfhi(h0.y);
    acc[4] += bflo(h0.z); acc[5] += bfhi(h0.z);
    acc[6] += bflo(h0.w); acc[7] += bfhi(h0.w);
  }
}

__device__ __forceinline__ uint4 ln_relu_pack(
    float v[8], int sub, const float* __restrict__ gam, const float* __restrict__ bet) {
  float s = 0.f, q = 0.f;
#pragma unroll
  for (int j = 0; j < 8; ++j) { s += v[j]; q += v[j] * v[j]; }
#pragma unroll
  for (int o = 1; o < 16; o <<= 1) {
    s += __shfl_xor(s, o);
    q += __shfl_xor(q, o);
  }
  float m = s * (1.0f / 128.0f);
  float var = q * (1.0f / 128.0f) - m * m;
  float rs = rsqrtf(var + 1e-5f);
  float4 g0 = reinterpret_cast<const float4*>(gam)[sub * 2];
  float4 g1 = reinterpret_cast<const float4*>(gam)[sub * 2 + 1];
  float4 e0 = reinterpret_cast<const float4*>(bet)[sub * 2];
  float4 e1 = reinterpret_cast<const float4*>(bet)[sub * 2 + 1];
  uint4 ov;
  ov.x = packbf(fmaxf((v[0] - m) * rs * g0.x + e0.x, 0.f), fmaxf((v[1] - m) * rs * g0.y + e0.y, 0.f));
  ov.y = packbf(fmaxf((v[2] - m) * rs * g0.z + e0.z, 0.f), fmaxf((v[3] - m) * rs * g0.w + e0.w, 0.f));
  ov.z = packbf(fmaxf((v[4] - m) * rs * g1.x + e1.x, 0.f), fmaxf((v[5] - m) * rs * g1.y + e1.y, 0.f));
  ov.w = packbf(fmaxf((v[6] - m) * rs * g1.z + e1.z, 0.f), fmaxf((v[7] - m) * rs * g1.w + e1.w, 0.f));
  return ov;
}

__device__ __forceinline__ void scale_bias(
    float acc[8], float di, int sub, const float* __restrict__ bias, float v[8]) {
  float4 b0v = reinterpret_cast<const float4*>(bias)[sub * 2];
  float4 b1v = reinterpret_cast<const float4*>(bias)[sub * 2 + 1];
  v[0] = acc[0] * di + b0v.x; v[1] = acc[1] * di + b0v.y;
  v[2] = acc[2] * di + b0v.z; v[3] = acc[3] * di + b0v.w;
  v[4] = acc[4] * di + b1v.x; v[5] = acc[5] * di + b1v.y;
  v[6] = acc[6] * di + b1v.z; v[7] = acc[7] * di + b1v.w;
}

// ---------- K1: weight pack (384 blocks) + bucket histogram (64 blocks) ----------
__global__ __launch_bounds__(256) void packhist(
    const float* __restrict__ Wa, const float* __restrict__ Wb, const float* __restrict__ Wc,
    unsigned short* __restrict__ P, const int* __restrict__ dst,
    unsigned int* __restrict__ Hist, int E) {
  __shared__ unsigned int cnt[256];
  int bid = blockIdx.x;
  int t = threadIdx.x;
  if (bid >= 384) {
    int hb = bid - 384;
    cnt[t] = 0u;
    __syncthreads();
    int chunk = (E + 63) >> 6;
    int lo = hb * chunk, hi = min(E, lo + chunk);
    for (int e = lo + t; e < hi; e += 256)
      atomicAdd(&cnt[((unsigned int)dst[e]) >> 8], 1u);
    __syncthreads();
    Hist[hb * 256 + t] = cnt[t];
    return;
  }
  int gidx = bid * 256 + t;
  int which = gidx >> 15;
  int idx = gidx & 32767;
  const float* W = (which == 0) ? Wa : (which == 1) ? Wb : Wc;
  int j = idx & 15;
  int lane = (idx >> 4) & 63;
  int tt = (idx >> 10) & 7;
  int c = (idx >> 13) & 3;
  int k = c * 32 + (lane >> 4) * 8 + (j & 7);
  int nn = tt * 16 + (lane & 15);
  float f = W[k * 128 + nn];
  unsigned short hi16 = f2bf(f);
  unsigned short outv = (j < 8) ? hi16 : f2bf(f - bf2f(hi16));
  P[gidx] = outv;
}

// ---------- K3: layer-1 GEMM + bucket scatter (scatter self-computes bases from Hist) ----------
__global__ __launch_bounds__(256) void gemm1_scatter(
    const float* __restrict__ in, const unsigned short* __restrict__ P,
    unsigned short* __restrict__ out, int n,
    const int* __restrict__ src, const int* __restrict__ dst,
    const unsigned int* __restrict__ Hist, unsigned int* __restrict__ EP,
    int E, int gemmBlocks) {
  __shared__ unsigned int cur[256];
  __shared__ int scanb[256];
  int tid = threadIdx.x;
  if ((int)blockIdx.x >= gemmBlocks) {
    int sb = (int)blockIdx.x - gemmBlocks;
    // local base: before = sum_{b<sb} Hist[b][t]; total over all b; Bstart via LDS scan
    unsigned int before = 0, total = 0;
    for (int b = 0; b < 64; ++b) {
      unsigned int hv = Hist[b * 256 + tid];
      if (b < sb) before += hv;
      total += hv;
    }
    int v = (int)total;
    scanb[tid] = v;
    __syncthreads();
    for (int o = 1; o < 256; o <<= 1) {
      int add = (tid >= o) ? scanb[tid - o] : 0;
      __syncthreads();
      scanb[tid] += add;
      __syncthreads();
    }
    cur[tid] = (unsigned int)(scanb[tid] - v) + before;
    __syncthreads();
    int chunk = (E + 63) >> 6;
    int lo = sb * chunk, hi = min(E, lo + chunk);
    for (int e = lo + tid; e < hi; e += 256) {
      unsigned int d = (unsigned int)dst[e];
      unsigned int s = (unsigned int)src[e];
      unsigned int pos = atomicAdd(&cur[d >> 8], 1u);
      EP[pos] = ((d & 255u) << 16) | s;  // N <= 65536
    }
    return;
  }
  int wave = tid >> 6, lane = tid & 63;
  int quad = lane >> 4, c16 = lane & 15;
  int base = blockIdx.x * 64 + wave * 16;
  int m = base + c16;

  f4v acc[8];
#pragma unroll
  for (int t = 0; t < 8; ++t) acc[t] = (f4v){0.f, 0.f, 0.f, 0.f};

  for (int c = 0; c < 4; ++c) {
    s8v ah, al;
    float v[8];
    if (m < n) {
      const float4* xp = reinterpret_cast<const float4*>(in + (size_t)m * 128 + c * 32 + quad * 8);
      float4 v0 = xp[0], v1 = xp[1];
      v[0] = v0.x; v[1] = v0.y; v[2] = v0.z; v[3] = v0.w;
      v[4] = v1.x; v[5] = v1.y; v[6] = v1.z; v[7] = v1.w;
    } else {
#pragma unroll
      for (int j = 0; j < 8; ++j) v[j] = 0.f;
    }
#pragma unroll
    for (int j = 0; j < 8; ++j) {
      unsigned short h = f2bf(v[j]);
      ah[j] = (short)h;
      al[j] = (short)f2bf(v[j] - bf2f(h));
    }
#pragma unroll
    for (int t = 0; t < 8; ++t) {
      const s8v* bp = reinterpret_cast<const s8v*>(&P[((c * 8 + t) * 64 + lane) * 16]);
      s8v bh = bp[0], bl = bp[1];
      acc[t] = __builtin_amdgcn_mfma_f32_16x16x32_bf16(ah, bh, acc[t], 0, 0, 0);
      acc[t] = __builtin_amdgcn_mfma_f32_16x16x32_bf16(ah, bl, acc[t], 0, 0, 0);
      acc[t] = __builtin_amdgcn_mfma_f32_16x16x32_bf16(al, bh, acc[t], 0, 0, 0);
    }
  }
#pragma unroll
  for (int t = 0; t < 8; ++t)
#pragma unroll
    for (int r = 0; r < 4; ++r) {
      int mm = base + quad * 4 + r;
      if (mm < n) out[(size_t)mm * 128 + t * 16 + c16] = f2bf(acc[t][r]);
    }
}

// ---------- K4: per-bucket fine CSR (self-computes Bstart from Hist) ----------
__global__ __launch_bounds__(256) void fine_csr(
    const unsigned int* __restrict__ EP, const unsigned int* __restrict__ Hist,
    int* __restrict__ offs, float* __restrict__ dinv, int* __restrict__ col, int n, int E) {
  __shared__ unsigned int cnt[256];
  __shared__ int sh[256];
  __shared__ unsigned int cur[256];
  __shared__ int tot[256];
  __shared__ int bst[256];
  int bk = blockIdx.x;
  int t = threadIdx.x;
  unsigned int total = 0;
  for (int b = 0; b < 64; ++b) total += Hist[b * 256 + t];
  tot[t] = (int)total;
  bst[t] = (int)total;
  __syncthreads();
  for (int o = 1; o < 256; o <<= 1) {
    int add = (t >= o) ? bst[t - o] : 0;
    __syncthreads();
    bst[t] += add;
    __syncthreads();
  }
  // exclusive start of bucket t = bst[t] - tot[t]
  unsigned int rlo = (unsigned int)(bst[bk] - tot[bk]);
  unsigned int rhi = rlo + (unsigned int)tot[bk];
  if (bk == 0 && t == 0) offs[n] = E;
  cnt[t] = 0u;
  __syncthreads();
  for (unsigned int i = rlo + t; i < rhi; i += 256)
    atomicAdd(&cnt[EP[i] >> 16], 1u);
  __syncthreads();
  int v = (int)cnt[t];
  sh[t] = v;
  __syncthreads();
  for (int o = 1; o < 256; o <<= 1) {
    int add = (t >= o) ? sh[t - o] : 0;
    __syncthreads();
    sh[t] += add;
    __syncthreads();
  }
  int pre = sh[t] - v;
  int node = bk * 256 + t;
  if (node < n) {
    offs[node] = (int)(rlo + pre);
    dinv[node] = rsqrtf((float)(v + 1));
  }
  cur[t] = rlo + (unsigned int)pre;
  __syncthreads();
  for (unsigned int i = rlo + t; i < rhi; i += 256) {
    unsigned int w = EP[i];
    unsigned int dl = w >> 16;
    unsigned int pos = atomicAdd(&cur[dl], 1u);
    col[pos] = (int)(w & 0xffffu);
  }
}

// ---------- K5: fused gather1+LN -> LDS (32 nodes) -> GEMM(W2) -> out (pre-scaled by dinv) ----------
__global__ __launch_bounds__(256) void gather_gemm(
    const int* __restrict__ offs, const int* __restrict__ col,
    const float* __restrict__ dinv, const unsigned short* __restrict__ h,
    const float* __restrict__ bias, const float* __restrict__ gam,
    const float* __restrict__ bet, const unsigned short* __restrict__ P,
    unsigned short* __restrict__ out, int n) {
  __shared__ unsigned short A[32 * LDA];
  int tid = threadIdx.x;
  int wave = tid >> 6, lane = tid & 63;
  int grp = lane >> 4, sub = lane & 15;
  const uint4* hu = reinterpret_cast<const uint4*>(h);
  int blk = blockIdx.x * 32;
  for (int it = 0; it < 2; ++it) {
    int li = it * 16 + wave * 4 + grp;
    int i = blk + li;
    uint4 ov;
    if (i < n) {
      float acc[8], v[8];
      float di = gather_node(i, sub, offs, col, dinv, hu, acc);
      scale_bias(acc, di, sub, bias, v);
      ov = ln_relu_pack(v, sub, gam, bet);
    } else {
      ov = make_uint4(0u, 0u, 0u, 0u);
    }
    *reinterpret_cast<uint4*>(&A[li * LDA + sub * 8]) = ov;
  }
  __syncthreads();
  int quad = lane >> 4, c16 = lane & 15;
  int rowgrp = wave & 1, colhalf = wave >> 1;
  f4v acc[4];
#pragma unroll
  for (int t = 0; t < 4; ++t) acc[t] = (f4v){0.f, 0.f, 0.f, 0.f};
  int liA = rowgrp * 16 + c16;
  for (int c = 0; c < 4; ++c) {
    s8v ah = *reinterpret_cast<const s8v*>(&A[liA * LDA + c * 32 + quad * 8]);
#pragma unroll
    for (int t4 = 0; t4 < 4; ++t4) {
      int t = colhalf * 4 + t4;
      const s8v* bp = reinterpret_cast<const s8v*>(&P[((c * 8 + t) * 64 + lane) * 16]);
      s8v bh = bp[0], bl = bp[1];
      acc[t4] = __builtin_amdgcn_mfma_f32_16x16x32_bf16(ah, bh, acc[t4], 0, 0, 0);
      acc[t4] = __builtin_amdgcn_mfma_f32_16x16x32_bf16(ah, bl, acc[t4], 0, 0, 0);
    }
  }
  float dv[4];
#pragma unroll
  for (int r = 0; r < 4; ++r) {
    int mm = blk + rowgrp * 16 + quad * 4 + r;
    dv[r] = (mm < n) ? dinv[mm] : 0.f;
  }
#pragma unroll
  for (int t4 = 0; t4 < 4; ++t4) {
    int t = colhalf * 4 + t4;
#pragma unroll
    for (int r = 0; r < 4; ++r) {
      int mm = blk + rowgrp * 16 + quad * 4 + r;
      if (mm < n) out[(size_t)mm * 128 + t * 16 + c16] = f2bf(acc[t4][r] * dv[r]);
    }
  }
}

// ---------- K6: fused gather2 (pure-sum) + LN (+hout) + gate GEMM -> gate[N] ----------
__global__ __launch_bounds__(256) void gather_gate(
    const int* __restrict__ offs, const int* __restrict__ col,
    const float* __restrict__ dinv, const unsigned short* __restrict__ h,
    const float* __restrict__ bias, const float* __restrict__ gam,
    const float* __restrict__ bet, const unsigned short* __restrict__ P,
    const float* __restrict__ gb1, const float* __restrict__ gw2,
    const float* __restrict__ gb2, unsigned short* __restrict__ hout,
    float* __restrict__ gate, int n) {
  __shared__ unsigned short A[32 * LDA];
  __shared__ float pbuf[4][16];
  int tid = threadIdx.x;
  int wave = tid >> 6, lane = tid & 63;
  int grp = lane >> 4, sub = lane & 15;
  const uint4* hu = reinterpret_cast<const uint4*>(h);
  int blk = blockIdx.x * 32;
  for (int it = 0; it < 2; ++it) {
    int li = it * 16 + wave * 4 + grp;
    int i = blk + li;
    uint4 ov;
    if (i < n) {
      float acc[8], v[8];
      gather_sum(i, sub, offs, col, hu, acc);
      scale_bias(acc, dinv[i], sub, bias, v);
      ov = ln_relu_pack(v, sub, gam, bet);
      reinterpret_cast<uint4*>(hout)[(size_t)i * 16 + sub] = ov;
    } else {
      ov = make_uint4(0u, 0u, 0u, 0u);
    }
    *reinterpret_cast<uint4*>(&A[li * LDA + sub * 8]) = ov;
  }
  __syncthreads();
  int quad = lane >> 4, c16 = lane & 15;
  int rowgrp = wave & 1, colhalf = wave >> 1;
  f4v acc[4];
#pragma unroll
  for (int t = 0; t < 4; ++t) acc[t] = (f4v){0.f, 0.f, 0.f, 0.f};
  int liA = rowgrp * 16 + c16;
  for (int c = 0; c < 4; ++c) {
    s8v ah = *reinterpret_cast<const s8v*>(&A[liA * LDA + c * 32 + quad * 8]);
#pragma unroll
    for (int t4 = 0; t4 < 4; ++t4) {
      int t = colhalf * 4 + t4;
      const s8v* bp = reinterpret_cast<const s8v*>(&P[((c * 8 + t) * 64 + lane) * 16]);
      s8v bh = bp[0], bl = bp[1];
      acc[t4] = __builtin_amdgcn_mfma_f32_16x16x32_bf16(ah, bh, acc[t4], 0, 0, 0);
      acc[t4] = __builtin_amdgcn_mfma_f32_16x16x32_bf16(ah, bl, acc[t4], 0, 0, 0);
    }
  }
  float bv[4], g2[4];
#pragma unroll
  for (int t4 = 0; t4 < 4; ++t4) {
    int t = colhalf * 4 + t4;
    bv[t4] = gb1[t * 16 + c16];
    g2[t4] = gw2[t * 16 + c16];
  }
#pragma unroll
  for (int r = 0; r < 4; ++r) {
    float p = 0.f;
#pragma unroll
    for (int t4 = 0; t4 < 4; ++t4)
      p += fmaxf(acc[t4][r] + bv[t4], 0.f) * g2[t4];
#pragma unroll
    for (int o = 1; o < 16; o <<= 1) p += __shfl_xor(p, o);
    if (c16 == 0) pbuf[wave][quad * 4 + r] = p;
  }
  __syncthreads();
  if (tid < 32) {
    int rg = tid >> 4, local = tid & 15;
    int mm = blk + tid;
    if (mm < n) gate[mm] = pbuf[rg][local] + pbuf[rg + 2][local] + gb2[0];
  }
}

// ---------- pooling + classifier fused ----------
__global__ __launch_bounds__(256) void pool_cls(
    float* __restrict__ gate, const unsigned short* __restrict__ h,
    const int* __restrict__ batch,
    const float* __restrict__ w1, const float* __restrict__ b1,
    const float* __restrict__ w2, const float* __restrict__ b2,
    float* __restrict__ out, int n) {
  int g = blockIdx.x;
  int tid = threadIdx.x;
  __shared__ float red[256];
  __shared__ float red2[256];
  __shared__ float p[128];
  __shared__ float r[128];
  int lo = lower_bound_i(batch, n, g);
  int hi = lower_bound_i(batch, n, g + 1);
  if (lo >= hi) {
    if (tid < 128) p[tid] = 0.0f;
  } else {
    float m = -3.0e38f;
    for (int i = lo + tid; i < hi; i += 256) m = fmaxf(m, gate[i]);
    red[tid] = m;
    __syncthreads();
#pragma unroll
    for (int o = 128; o > 0; o >>= 1) {
      if (tid < o) red[tid] = fmaxf(red[tid], red[tid + o]);
      __syncthreads();
    }
    m = red[0];
    __syncthreads();
    float s = 0.0f;
    for (int i = lo + tid; i < hi; i += 256) {
      float e = __expf(gate[i] - m);
      gate[i] = e;
      s += e;
    }
    red[tid] = s;
    __syncthreads();
#pragma unroll
    for (int o = 128; o > 0; o >>= 1) {
      if (tid < o) red[tid] += red[tid + o];
      __syncthreads();
    }
    float inv = 1.0f / red[0];
    __syncthreads();
    const unsigned int* hu = reinterpret_cast<const unsigned int*>(h);
    int j = tid & 63, rgp = tid >> 6;
    float a0 = 0.f, a1 = 0.f;
    int i = lo + rgp;
    for (; i + 12 < hi; i += 16) {
      unsigned int p0 = hu[(size_t)i * 64 + j];
      unsigned int p1 = hu[(size_t)(i + 4) * 64 + j];
      unsigned int p2 = hu[(size_t)(i + 8) * 64 + j];
      unsigned int p3 = hu[(size_t)(i + 12) * 64 + j];
      float w0 = gate[i], w1v = gate[i + 4], w2v = gate[i + 8], w3v = gate[i + 12];
      a0 += bflo(p0) * w0 + bflo(p1) * w1v + bflo(p2) * w2v + bflo(p3) * w3v;
      a1 += bfhi(p0) * w0 + bfhi(p1) * w1v + bfhi(p2) * w2v + bfhi(p3) * w3v;
    }
    for (; i < hi; i += 4) {
      unsigned int p0 = hu[(size_t)i * 64 + j];
      float w0 = gate[i];
      a0 += bflo(p0) * w0;
      a1 += bfhi(p0) * w0;
    }
    red[tid] = a0;
    red2[tid] = a1;
    __syncthreads();
    if (tid < 64) {
      p[2 * tid]     = (red[tid] + red[tid + 64] + red[tid + 128] + red[tid + 192]) * inv;
      p[2 * tid + 1] = (red2[tid] + red2[tid + 64] + red2[tid + 128] + red2[tid + 192]) * inv;
    }
  }
  __syncthreads();
  int j = tid & 127, half = tid >> 7;
  float acc = 0.0f;
#pragma unroll 8
  for (int k = half * 64; k < half * 64 + 64; ++k)
    acc = fmaf(p[k], w1[k * 128 + j], acc);
  red[tid] = acc;
  __syncthreads();
  if (tid < 128) r[tid] = fmaxf(red[tid] + red[tid + 128] + b1[tid], 0.0f);
  __syncthreads();
  if (tid < 2) {
    float a = 0.0f;
    for (int k = 0; k < 128; ++k) a = fmaf(r[k], w2[k * 2 + tid], a);
    out[g * 2 + tid] = a + b2[tid];
  }
}

static inline size_t alup(size_t x) { return (x + 255) & ~(size_t)255; }

extern "C" void kernel_launch(void* const* d_in, const int* in_sizes, int n_in,
                              void* d_out, int out_size, void* d_ws, size_t ws_size,
                              hipStream_t stream) {
  const float* x    = (const float*)d_in[0];
  const int*   ei   = (const int*)d_in[1];
  const int*   bat  = (const int*)d_in[2];
  const float* W1   = (const float*)d_in[3];
  const float* b1   = (const float*)d_in[4];
  const float* ln1g = (const float*)d_in[5];
  const float* ln1b = (const float*)d_in[6];
  const float* W2   = (const float*)d_in[7];
  const float* b2   = (const float*)d_in[8];
  const float* ln2g = (const float*)d_in[9];
  const float* ln2b = (const float*)d_in[10];
  const float* gw1  = (const float*)d_in[11];
  const float* gb1  = (const float*)d_in[12];
  const float* gw2  = (const float*)d_in[13];
  const float* gb2  = (const float*)d_in[14];
  const float* cw1  = (const float*)d_in[15];
  const float* cb1  = (const float*)d_in[16];
  const float* cw2  = (const float*)d_in[17];
  const float* cb2  = (const float*)d_in[18];

  const int N = in_sizes[2];
  const int E = in_sizes[1] / 2;
  const int G = out_size / 2;
  const int* src = ei;
  const int* dst = ei + E;

  int mfmaB = (N + 63) / 64;
  int fuseB = (N + 31) / 32;
  int NB = (N + 255) / 256;

  char* base = (char*)d_ws;
  unsigned int* Hist = (unsigned int*)base;   base += alup((size_t)64 * 256 * 4);
  unsigned int* EP = (unsigned int*)base;     base += alup((size_t)E * 4);
  float* dinv = (float*)base;                 base += alup((size_t)N * 4);
  int* offs = (int*)base;                     base += alup((size_t)(N + 1) * 4);
  int* col = (int*)base;                      base += alup((size_t)E * 4);
  unsigned short* pW = (unsigned short*)base; base += alup((size_t)3 * 32768 * 2);
  unsigned short* hbuf = (unsigned short*)base;  base += alup((size_t)N * 128 * 2);
  unsigned short* hbuf2 = (unsigned short*)base; base += alup((size_t)N * 128 * 2);
  unsigned short* hout = (unsigned short*)base;  base += alup((size_t)N * 128 * 2);
  float* gate = (float*)base;                 base += alup((size_t)N * 4);

  unsigned short* pW1 = pW;
  unsigned short* pW2 = pW + 32768;
  unsigned short* pG1 = pW + 65536;

  float* out = (float*)d_out;

  packhist<<<384 + 64, 256, 0, stream>>>(W1, W2, gw1, pW, dst, Hist, E);
  gemm1_scatter<<<mfmaB + 64, 256, 0, stream>>>(x, pW1, hbuf, N,
                                                src, dst, Hist, EP, E, mfmaB);
  fine_csr<<<NB, 256, 0, stream>>>(EP, Hist, offs, dinv, col, N, E);
  gather_gemm<<<fuseB, 256, 0, stream>>>(offs, col, dinv, hbuf, b1, ln1g, ln1b,
                                         pW2, hbuf2, N);
  gather_gate<<<fuseB, 256, 0, stream>>>(offs, col, dinv, hbuf2, b2, ln2g, ln2b,
                                         pG1, gb1, gw2, gb2, hout, gate, N);
  pool_cls<<<G, 256, 0, stream>>>(gate, hout, bat, cw1, cb1, cw2, cb2, out, N);
}